// Round 1
// baseline (804.106 us; speedup 1.0000x reference)
//
#include <hip/hip_runtime.h>
#include <stdint.h>

// ---------------------------------------------------------------------------
// TopicRNN_GCN: h = lrelu(adj @ lrelu(adj @ (maxgather(emb) @ W1) + b1) @ W2' ...)
// Strategy: bf16 MFMA for everything matmul-shaped; adj converted to bf16 once.
// All GEMMs: A (M x Kpad) row-major bf16, Bt (N x Kpad) row-major bf16 (B
// pre-transposed) so both LDS tiles stage identically via global_load_lds(16B)
// and fragments are contiguous ds_read_b128 along K (m97 structure).
// Big GEMMs (K=10048) use split-K=4 -> 632 blocks (~2.5/CU) + reduce epilogue.
// ---------------------------------------------------------------------------

#define N_NODES 10000
#define MP      10112          // M padded to 79*128
#define KP      10048          // adj K padded to multiple of 64
#define EMB     300
#define EKP     320            // embed K padded
#define HID     256
#define SLOPE   0.01f

typedef __attribute__((ext_vector_type(8))) short          bf16x8;
typedef __attribute__((ext_vector_type(4))) float          f32x4;
typedef __attribute__((ext_vector_type(8))) unsigned short ushort8;
typedef __attribute__((ext_vector_type(4))) unsigned short ushort4v;

__device__ __forceinline__ unsigned short f2b(float f) {
    union { float f; unsigned u; } v; v.f = f;
    unsigned r = v.u + 0x7FFFu + ((v.u >> 16) & 1u);   // round-nearest-even
    return (unsigned short)(r >> 16);
}

__device__ __forceinline__ void g2l16(const void* gptr, const void* ldsptr) {
    __builtin_amdgcn_global_load_lds(
        (const __attribute__((address_space(1))) void*)(uintptr_t)gptr,
        (__attribute__((address_space(3))) void*)(uint32_t)(uintptr_t)ldsptr,
        16, 0, 0);
}

// ---------------------------------------------------------------------------
// adj fp32 (10000x10000) -> bf16 (MP x KP), zero-padded
__global__ void convert_adj(const float* __restrict__ adj,
                            unsigned short* __restrict__ out) {
    const int r  = blockIdx.y;
    const int c0 = (blockIdx.x * 256 + threadIdx.x) * 8;
    if (c0 >= KP) return;
    ushort8 v = {};
    if (r < N_NODES && c0 + 8 <= N_NODES) {
        const float* src = adj + (size_t)r * N_NODES + c0;
        f32x4 f0 = *(const f32x4*)src;
        f32x4 f1 = *(const f32x4*)(src + 4);
#pragma unroll
        for (int t = 0; t < 4; ++t) { v[t] = f2b(f0[t]); v[t + 4] = f2b(f1[t]); }
    }
    *(ushort8*)(out + (size_t)r * KP + c0) = v;
}

// x[i][e] = max_r emb[nodes[(i+1)*8+r]][e]  -> bf16 (MP x EKP), zero-padded
__global__ void gather_max_x(const int* __restrict__ nodes,
                             const float* __restrict__ emb,
                             unsigned short* __restrict__ xb) {
    const int i = blockIdx.x;
    unsigned short* xrow = xb + (size_t)i * EKP;
    if (i >= N_NODES) {
        for (int e = threadIdx.x; e < EKP; e += 256) xrow[e] = 0;
        return;
    }
    const int* idx = nodes + (i + 1) * 8;
    int id[8];
#pragma unroll
    for (int r = 0; r < 8; ++r) id[r] = idx[r];
    for (int e = threadIdx.x; e < EKP; e += 256) {
        unsigned short v = 0;
        if (e < EMB) {
            float m = emb[(size_t)id[0] * EMB + e];
#pragma unroll
            for (int r = 1; r < 8; ++r) m = fmaxf(m, emb[(size_t)id[r] * EMB + e]);
            v = f2b(m);
        }
        xrow[e] = v;
    }
}

// W (K x 256) fp32 -> Wt (256 x Kpad) bf16, zero-padded
__global__ void prep_w(const float* __restrict__ W, unsigned short* __restrict__ Wt,
                       int K, int Kpad) {
    const int o = blockIdx.x * 256 + threadIdx.x;
    if (o >= HID * Kpad) return;
    const int n = o / Kpad, k = o % Kpad;
    Wt[o] = (k < K) ? f2b(W[(size_t)k * HID + n]) : 0;
}

// bf16 transpose: in (>=KP rows x 256) -> out (256 x KP)
__global__ void transpose_bf16(const unsigned short* __restrict__ in,
                               unsigned short* __restrict__ out) {
    __shared__ unsigned short t[32][33];
    const int kt = blockIdx.x * 32, nt = blockIdx.y * 32;
    const int x = threadIdx.x, y0 = threadIdx.y;
#pragma unroll
    for (int yy = y0; yy < 32; yy += 8)
        t[yy][x] = in[(size_t)(kt + yy) * HID + nt + x];
    __syncthreads();
#pragma unroll
    for (int yy = y0; yy < 32; yy += 8)
        out[(size_t)(nt + yy) * KP + kt + x] = t[x][yy];
}

// ---------------------------------------------------------------------------
// MFMA GEMM, 128x128 tile, BK=64, 4 waves (each 64x64 = 4x4 of 16x16x32).
// MODE 0: write bf16 C (M x ldC).  MODE 1: write fp32 partial (split-K via z).
template <int MODE>
__launch_bounds__(256, 3)
__global__ void gemm_bt(const unsigned short* __restrict__ A, int ldA,
                        const unsigned short* __restrict__ Bt, int ldB,
                        void* __restrict__ Cout, int ldC,
                        int Ktot, int kChunk, size_t partStride) {
    const int tid  = threadIdx.x;
    const int wave = tid >> 6, lane = tid & 63;
    const int wm = wave >> 1, wn = wave & 1;
    const int l16 = lane & 15, quad = lane >> 4;
    const int tileM = blockIdx.x * 128;
    const int tileN = blockIdx.y * 128;
    const int kStart = (MODE == 1) ? (int)blockIdx.z * kChunk : 0;
    const int kLen   = min(kChunk, Ktot - kStart);

    __shared__ unsigned short ldsA[128 * 64];
    __shared__ unsigned short ldsB[128 * 64];

    const unsigned short* Ag = A  + (size_t)(tileM + (tid >> 3)) * ldA + kStart + ((tid & 7) * 8);
    const unsigned short* Bg = Bt + (size_t)(tileN + (tid >> 3)) * ldB + kStart + ((tid & 7) * 8);
    unsigned short* lA = &ldsA[tid * 8];
    unsigned short* lB = &ldsB[tid * 8];
    const size_t aStep = (size_t)32 * ldA;
    const size_t bStep = (size_t)32 * ldB;

    const unsigned short* pa0 = &ldsA[(wm * 64 + l16) * 64 + quad * 8];
    const unsigned short* pb0 = &ldsB[(wn * 64 + l16) * 64 + quad * 8];

    f32x4 acc[4][4] = {};
    const int kIters = kLen >> 6;

    for (int kt = 0; kt < kIters; ++kt) {
        __syncthreads();                    // consumers of previous tile done
#pragma unroll
        for (int i = 0; i < 4; ++i) {
            g2l16(Ag + i * aStep, lA + i * 2048);
            g2l16(Bg + i * bStep, lB + i * 2048);
        }
        Ag += 64; Bg += 64;
        __syncthreads();                    // drains vmcnt -> LDS tile ready
#pragma unroll
        for (int kk = 0; kk < 64; kk += 32) {
            bf16x8 af[4], bq[4];
#pragma unroll
            for (int i = 0; i < 4; ++i) af[i] = *(const bf16x8*)(pa0 + i * 1024 + kk);
#pragma unroll
            for (int j = 0; j < 4; ++j) bq[j] = *(const bf16x8*)(pb0 + j * 1024 + kk);
#pragma unroll
            for (int i = 0; i < 4; ++i)
#pragma unroll
                for (int j = 0; j < 4; ++j)
                    acc[i][j] = __builtin_amdgcn_mfma_f32_16x16x32_bf16(
                        af[i], bq[j], acc[i][j], 0, 0, 0);
        }
    }

    if (MODE == 0) {
        unsigned short* C = (unsigned short*)Cout;
#pragma unroll
        for (int i = 0; i < 4; ++i)
#pragma unroll
            for (int r = 0; r < 4; ++r) {
                const int row = tileM + wm * 64 + i * 16 + quad * 4 + r;
#pragma unroll
                for (int j = 0; j < 4; ++j) {
                    const int col = tileN + wn * 64 + j * 16 + l16;
                    C[(size_t)row * ldC + col] = f2b(acc[i][j][r]);
                }
            }
    } else {
        float* C = (float*)Cout + (size_t)blockIdx.z * partStride;
#pragma unroll
        for (int i = 0; i < 4; ++i)
#pragma unroll
            for (int r = 0; r < 4; ++r) {
                const int row = tileM + wm * 64 + i * 16 + quad * 4 + r;
#pragma unroll
                for (int j = 0; j < 4; ++j) {
                    const int col = tileN + wn * 64 + j * 16 + l16;
                    C[(size_t)row * ldC + col] = acc[i][j][r];
                }
            }
    }
}

// sum 4 split-K partials + bias, leaky-relu; OUT_BF16: bf16 (all MP rows),
// else fp32 to d_out (rows < outRows only).
template <int OUT_BF16>
__global__ void reduce_bias_lrelu(const float* __restrict__ parts, size_t partStride,
                                  const float* __restrict__ bias,
                                  void* __restrict__ out, int outRows) {
    const int idx = blockIdx.x * 256 + threadIdx.x;
    const int e4  = idx * 4;
    const int row = e4 >> 8;
    const int col = e4 & 255;
    if (row >= MP) return;
    f32x4 s = *(const f32x4*)(parts + e4);
#pragma unroll
    for (int p = 1; p < 4; ++p) s += *(const f32x4*)(parts + p * partStride + e4);
    s += *(const f32x4*)(bias + col);
#pragma unroll
    for (int t = 0; t < 4; ++t) s[t] = s[t] > 0.0f ? s[t] : SLOPE * s[t];
    if (OUT_BF16) {
        ushort4v o;
#pragma unroll
        for (int t = 0; t < 4; ++t) o[t] = f2b(s[t]);
        *(ushort4v*)((unsigned short*)out + e4) = o;
    } else if (row < outRows) {
        *(f32x4*)((float*)out + e4) = s;
    }
}

// ---------------------------------------------------------------------------
extern "C" void kernel_launch(void* const* d_in, const int* in_sizes, int n_in,
                              void* d_out, int out_size, void* d_ws, size_t ws_size,
                              hipStream_t stream) {
    const int*   nodes = (const int*)d_in[0];
    const float* emb   = (const float*)d_in[1];
    const float* adj   = (const float*)d_in[2];
    const float* W1    = (const float*)d_in[3];
    const float* b1    = (const float*)d_in[4];
    const float* W2    = (const float*)d_in[5];
    const float* b2    = (const float*)d_in[6];

    char* ws = (char*)d_ws;
    size_t o = 0;
    unsigned short* adjb = (unsigned short*)(ws + o); o += (size_t)MP * KP * 2;   // 203.2 MB
    unsigned short* xb   = (unsigned short*)(ws + o); o += (size_t)MP * EKP * 2;  // 6.5 MB
    unsigned short* w1t  = (unsigned short*)(ws + o); o += (size_t)HID * EKP * 2;
    unsigned short* w2t  = (unsigned short*)(ws + o); o += (size_t)HID * HID * 2;
    unsigned short* u1   = (unsigned short*)(ws + o); o += (size_t)MP * HID * 2;
    unsigned short* u1t  = (unsigned short*)(ws + o); o += (size_t)HID * KP * 2;
    unsigned short* h1   = (unsigned short*)(ws + o); o += (size_t)MP * HID * 2;
    unsigned short* u2   = (unsigned short*)(ws + o); o += (size_t)MP * HID * 2;
    unsigned short* u2t  = (unsigned short*)(ws + o); o += (size_t)HID * KP * 2;
    float*          parts= (float*)(ws + o);          o += (size_t)4 * MP * HID * 4; // 41.4 MB

    const size_t PSTRIDE = (size_t)MP * HID;   // elements per split partial

    // 0) conversions / gather
    convert_adj <<<dim3(5, MP), 256, 0, stream>>>(adj, adjb);
    gather_max_x<<<MP, 256, 0, stream>>>(nodes, emb, xb);
    prep_w      <<<(HID * EKP + 255) / 256, 256, 0, stream>>>(W1, w1t, EMB, EKP);
    prep_w      <<<(HID * HID + 255) / 256, 256, 0, stream>>>(W2, w2t, HID, HID);

    // 1) u1 = x @ W1    (M x 256)
    gemm_bt<0><<<dim3(79, 2, 1), 256, 0, stream>>>(xb, EKP, w1t, EKP, u1, HID,
                                                   EKP, EKP, 0);
    transpose_bf16<<<dim3(KP / 32, HID / 32), dim3(32, 8), 0, stream>>>(u1, u1t);

    // 2) h1 = lrelu(adj @ u1 + b1)   split-K=4
    gemm_bt<1><<<dim3(79, 2, 4), 256, 0, stream>>>(adjb, KP, u1t, KP, parts, HID,
                                                   KP, 2560, PSTRIDE);
    reduce_bias_lrelu<1><<<(MP * HID / 4 + 255) / 256, 256, 0, stream>>>(
        parts, PSTRIDE, b1, h1, MP);

    // 3) u2 = h1 @ W2
    gemm_bt<0><<<dim3(79, 2, 1), 256, 0, stream>>>(h1, HID, w2t, HID, u2, HID,
                                                   HID, HID, 0);
    transpose_bf16<<<dim3(KP / 32, HID / 32), dim3(32, 8), 0, stream>>>(u2, u2t);

    // 4) out = lrelu(adj @ u2 + b2)  split-K=4, fp32 out
    gemm_bt<1><<<dim3(79, 2, 4), 256, 0, stream>>>(adjb, KP, u2t, KP, parts, HID,
                                                   KP, 2560, PSTRIDE);
    reduce_bias_lrelu<0><<<(MP * HID / 4 + 255) / 256, 256, 0, stream>>>(
        parts, PSTRIDE, b2, d_out, N_NODES);
}